// Round 5
// baseline (423.485 us; speedup 1.0000x reference)
//
#include <hip/hip_runtime.h>
#include <stdint.h>
#include <float.h>

#define NUM_SAMPLES 50
#define EPSF 1e-8f
#define PENALTY 1e-4f
#define REV_SCALE 0.1f

// grid 1: original vertices (N(0,1) coords)
#define G1 48
#define G1LO -5.0f
#define G1HI 5.0f
#define NCELL1 (G1*G1*G1)
// grid 2: original-face barycenters (sigma ~0.577)
#define G2 48
#define G2LO -3.5f
#define G2HI 3.5f
#define NCELL2 (G2*G2*G2)
// grid 3: sample-point buckets (query sorting only)
#define G3 32
#define G3LO -5.0f
#define G3HI 5.0f
#define NCELL3 (G3*G3*G3)

#define NTOTALL (NCELL1 + NCELL2 + NCELL3)   // 253952
#define NB 248                               // build-kernel blocks (co-resident on 256 CUs)
static_assert(NTOTALL == NB * 1024, "scan tiling");

#define GS 16          // lanes per query group
#define QBLOCKS 2048   // query kernel grid

// acc region (floats): fwd slots [0..1023] stride16; rev [1024..2047]; max bits [2048..3071];
// done counter int at [3072]; build barrier counters ints [3080..3087]. 16 KB memset covers all.
#define ACC_FLOATS 4096

// ---------------- JAX threefry2x32 (exact) ----------------
__device__ __forceinline__ uint32_t rotl32(uint32_t v, int d) {
  return (v << d) | (v >> (32 - d));
}

__device__ __forceinline__ void threefry2x32(uint32_t k0, uint32_t k1,
                                             uint32_t x0, uint32_t x1,
                                             uint32_t& o0, uint32_t& o1) {
  const uint32_t k2 = k0 ^ k1 ^ 0x1BD11BDAu;
  x0 += k0; x1 += k1;
#define TF_ROUND(r) { x0 += x1; x1 = rotl32(x1, (r)); x1 ^= x0; }
  TF_ROUND(13) TF_ROUND(15) TF_ROUND(26) TF_ROUND(6)
  x0 += k1; x1 += k2 + 1u;
  TF_ROUND(17) TF_ROUND(29) TF_ROUND(16) TF_ROUND(24)
  x0 += k2; x1 += k0 + 2u;
  TF_ROUND(13) TF_ROUND(15) TF_ROUND(26) TF_ROUND(6)
  x0 += k0; x1 += k1 + 3u;
  TF_ROUND(17) TF_ROUND(29) TF_ROUND(16) TF_ROUND(24)
  x0 += k1; x1 += k2 + 4u;
  TF_ROUND(13) TF_ROUND(15) TF_ROUND(26) TF_ROUND(6)
  x0 += k2; x1 += k0 + 5u;
#undef TF_ROUND
  o0 = x0; o1 = x1;
}

__device__ __forceinline__ float bits_to_uniform(uint32_t bits) {
  return __uint_as_float((bits >> 9) | 0x3f800000u) - 1.0f;
}

__device__ __forceinline__ float jax_uniform_at(uint32_t k0, uint32_t k1, uint32_t idx) {
  uint32_t o0, o1;
  threefry2x32(k0, k1, 0u, idx, o0, o1);
  return bits_to_uniform(o0 ^ o1);
}

__device__ __forceinline__ int cell_coord(float p, float lo, float invh, int G) {
  int i = (int)floorf((p - lo) * invh);
  return min(max(i, 0), G - 1);
}

// pure: sample id -> position + weight (exact JAX RNG; partitionable split of key(42))
__device__ __forceinline__ float4 gen_sample(int id, const float* __restrict__ sv,
                                             const int* __restrict__ sfc,
                                             const float* __restrict__ fp, int NFP) {
  int face = id / NUM_SAMPLES;
  uint32_t a0, a1, b0, b1;
  threefry2x32(0u, 42u, 0u, 0u, a0, a1);  // rk1
  threefry2x32(0u, 42u, 0u, 1u, b0, b1);  // rk2
  float r1 = jax_uniform_at(a0, a1, (uint32_t)id);
  float r2 = jax_uniform_at(b0, b1, (uint32_t)id);
  float sr1 = sqrtf(r1);
  float ca = 1.0f - sr1;
  float cb = sr1 * (1.0f - r2);
  float cc = sr1 * r2;
  int va = sfc[3*face], vb = sfc[3*face+1], vc = sfc[3*face+2];
  float px = ca*sv[3*va]   + cb*sv[3*vb]   + cc*sv[3*vc];
  float py = ca*sv[3*va+1] + cb*sv[3*vb+1] + cc*sv[3*vc+1];
  float pz = ca*sv[3*va+2] + cb*sv[3*vb+2] + cc*sv[3*vc+2];
  float w = (face < NFP) ? fp[face] : 0.0f;
  return make_float4(px, py, pz, w);
}

// pure: barycenter (+|.|^2) of face i of (v,f)
__device__ __forceinline__ float4 bary_of(const float* __restrict__ v,
                                          const int* __restrict__ f, int i) {
  int a = f[3*i], b = f[3*i+1], c = f[3*i+2];
  float x = (v[3*a]   + v[3*b]   + v[3*c])   / 3.0f;
  float y = (v[3*a+1] + v[3*b+1] + v[3*c+1]) / 3.0f;
  float z = (v[3*a+2] + v[3*b+2] + v[3*c+2]) / 3.0f;
  return make_float4(x, y, z, x*x + y*y + z*z);
}

// device-wide barrier; all NB blocks co-resident. Cross-phase data uses atomics only.
__device__ __forceinline__ void grid_barrier(int* ctr, int idx) {
  __syncthreads();
  if (threadIdx.x == 0) {
    __threadfence();
    atomicAdd(&ctr[idx], 1);
    while (atomicAdd(&ctr[idx], 0) < NB) { }
    __threadfence();
  }
  __syncthreads();
}

// ---------------- build: zero -> histogram -> scan -> scatter, one dispatch
__global__ __launch_bounds__(256) void build_kernel(
    const float* __restrict__ ov, const int* __restrict__ ofc,
    const float* __restrict__ sv, const int* __restrict__ sfc,
    const float* __restrict__ fp,
    float4* __restrict__ ob4, float4* __restrict__ sb4, float4* __restrict__ ov4,
    float4* __restrict__ sorted,
    int* __restrict__ cnt, int* __restrict__ cs, int* __restrict__ cur,
    int* __restrict__ bsum, int* __restrict__ barctr,
    int NOF, int NSF, int NOV, int NFP, int nsamp) {
  int t = threadIdx.x, b = blockIdx.x;
  int tid = b * 256 + t;
  const int NT = NB * 256;  // 63488

  // phase 0: zero cnt (atomics only -> no dirty plain-store L2 lines vs later atomics)
  {
    int base = tid * 4;
    atomicExch(&cnt[base], 0);   atomicExch(&cnt[base+1], 0);
    atomicExch(&cnt[base+2], 0); atomicExch(&cnt[base+3], 0);
  }
  grid_barrier(barctr, 0);

  // phase 1: barycenters/vertices (plain stores, consumed only after dispatch boundary)
  //          + histograms (atomicAdd)
  {
    const float invh1 = (float)G1 / (G1HI - G1LO);
    const float invh2 = (float)G2 / (G2HI - G2LO);
    const float invh3 = (float)G3 / (G3HI - G3LO);
    int total = NOF + NSF + NOV + nsamp;
    for (int i = tid; i < total; i += NT) {
      if (i < NOF) {
        float4 p = bary_of(ov, ofc, i);
        ob4[i] = p;
        int cx = cell_coord(p.x, G2LO, invh2, G2);
        int cy = cell_coord(p.y, G2LO, invh2, G2);
        int cz = cell_coord(p.z, G2LO, invh2, G2);
        atomicAdd(&cnt[NCELL1 + (cz*G2 + cy)*G2 + cx], 1);
      } else if (i < NOF + NSF) {
        int j = i - NOF;
        sb4[j] = bary_of(sv, sfc, j);
      } else if (i < NOF + NSF + NOV) {
        int j = i - NOF - NSF;
        float x = ov[3*j], y = ov[3*j+1], z = ov[3*j+2];
        ov4[j] = make_float4(x, y, z, x*x + y*y + z*z);
        int cx = cell_coord(x, G1LO, invh1, G1);
        int cy = cell_coord(y, G1LO, invh1, G1);
        int cz = cell_coord(z, G1LO, invh1, G1);
        atomicAdd(&cnt[(cz*G1 + cy)*G1 + cx], 1);
      } else {
        int j = i - NOF - NSF - NOV;
        float4 s = gen_sample(j, sv, sfc, fp, NFP);
        int cx = cell_coord(s.x, G3LO, invh3, G3);
        int cy = cell_coord(s.y, G3LO, invh3, G3);
        int cz = cell_coord(s.z, G3LO, invh3, G3);
        atomicAdd(&cnt[NCELL1 + NCELL2 + (cz*G3 + cy)*G3 + cx], 1);
      }
    }
  }
  grid_barrier(barctr, 1);

  // phase 2a: block-local scan of 1024 cells (atomic reads of cnt)
  __shared__ int lds[256];
  int gid = b * 256 + t;
  int4 c;
  c.x = atomicAdd(&cnt[4*gid],   0);
  c.y = atomicAdd(&cnt[4*gid+1], 0);
  c.z = atomicAdd(&cnt[4*gid+2], 0);
  c.w = atomicAdd(&cnt[4*gid+3], 0);
  int s01 = c.x + c.y;
  int tsum = s01 + c.z + c.w;
  lds[t] = tsum;
  __syncthreads();
  for (int d = 1; d < 256; d <<= 1) {
    int u = (t >= d) ? lds[t - d] : 0;
    __syncthreads();
    lds[t] += u;
    __syncthreads();
  }
  int incl = lds[t];
  if (t == 0) atomicExch(&bsum[b], lds[255]);
  grid_barrier(barctr, 2);

  // phase 2b: prefix over predecessor blocks, write cs (plain; query-only) + cur (atomic)
  __shared__ int wsum[4];
  __shared__ int boffS;
  int pre = 0;
  if (t < b) pre = atomicAdd(&bsum[t], 0);
  for (int o = 32; o > 0; o >>= 1) pre += __shfl_down(pre, o);
  if ((t & 63) == 0) wsum[t >> 6] = pre;
  __syncthreads();
  if (t == 0) boffS = wsum[0] + wsum[1] + wsum[2] + wsum[3];
  __syncthreads();
  int base = boffS + incl - tsum;
  int4 o4;
  o4.x = base;
  o4.y = base + c.x;
  o4.z = base + s01;
  o4.w = base + s01 + c.z;
  ((int4*)cs)[gid] = o4;
  atomicExch(&cur[4*gid],   o4.x);
  atomicExch(&cur[4*gid+1], o4.y);
  atomicExch(&cur[4*gid+2], o4.z);
  atomicExch(&cur[4*gid+3], o4.w);
  if (b == NB - 1 && t == 255) cs[NTOTALL] = boffS + incl;
  grid_barrier(barctr, 3);

  // phase 3: scatter (recompute points from pure inputs; cur via RMW; sorted plain -> query)
  {
    const float invh1 = (float)G1 / (G1HI - G1LO);
    const float invh2 = (float)G2 / (G2HI - G2LO);
    const float invh3 = (float)G3 / (G3HI - G3LO);
    int nsc = NOV + NOF + nsamp;
    for (int i = tid; i < nsc; i += NT) {
      float4 p; int cell;
      if (i < NOV) {
        float x = ov[3*i], y = ov[3*i+1], z = ov[3*i+2];
        p = make_float4(x, y, z, x*x + y*y + z*z);
        int cx = cell_coord(x, G1LO, invh1, G1);
        int cy = cell_coord(y, G1LO, invh1, G1);
        int cz = cell_coord(z, G1LO, invh1, G1);
        cell = (cz*G1 + cy)*G1 + cx;
      } else if (i < NOV + NOF) {
        p = bary_of(ov, ofc, i - NOV);
        int cx = cell_coord(p.x, G2LO, invh2, G2);
        int cy = cell_coord(p.y, G2LO, invh2, G2);
        int cz = cell_coord(p.z, G2LO, invh2, G2);
        cell = NCELL1 + (cz*G2 + cy)*G2 + cx;
      } else {
        p = gen_sample(i - NOV - NOF, sv, sfc, fp, NFP);
        int cx = cell_coord(p.x, G3LO, invh3, G3);
        int cy = cell_coord(p.y, G3LO, invh3, G3);
        int cz = cell_coord(p.z, G3LO, invh3, G3);
        cell = NCELL1 + NCELL2 + (cz*G3 + cy)*G3 + cx;
      }
      int idx = atomicAdd(&cur[cell], 1);
      sorted[idx] = p;
    }
  }
}

// ---------------- row-parallel cooperative 1-NN: lanes own ring ROWS (parallel cs chains)
__device__ __forceinline__ float group_min16(float v) {
  for (int o = 8; o > 0; o >>= 1) v = fminf(v, __shfl_xor(v, o, 16));
  return v;
}

__device__ float nn_group(float px, float py, float pz, float q2,
                          const int* __restrict__ cs, const float4* __restrict__ pts,
                          int G, float lo, float h, int cellofs, int lane) {
  const float invh = 1.0f / h;
  int ix = cell_coord(px, lo, invh, G);
  int iy = cell_coord(py, lo, invh, G);
  int iz = cell_coord(pz, lo, invh, G);
  float m2x = -2.0f*px, m2y = -2.0f*py, m2z = -2.0f*pz;
  float best = FLT_MAX;  // per-lane partial of t = d^2 - q2

  // r = 0: cooperative over the home cell
  {
    int cix = cellofs + (iz*G + iy)*G + ix;
    int s = cs[cix], e = cs[cix + 1];
    for (int i = s + lane; i < e; i += GS) {
      float4 v = pts[i];
      best = fminf(best, fmaf(v.z, m2z, fmaf(v.y, m2y, fmaf(v.x, m2x, v.w))));
    }
  }
  for (int r = 1; r < G; ++r) {
    float bmin = group_min16(best);
    float bd = (float)(r - 1) * h;
    if (bmin + q2 <= bd * bd) break;   // exact termination
    float dbest = bmin + q2;           // current best d^2 (inf if none yet)
    int z0 = max(iz - r, 0), z1 = min(iz + r, G - 1);
    int y0 = max(iy - r, 0), y1 = min(iy + r, G - 1);
    int x0 = max(ix - r, 0), x1 = min(ix + r, G - 1);
    int Y = y1 - y0 + 1;
    int nrows = Y * (z1 - z0 + 1);
    for (int rowi = lane; rowi < nrows; rowi += GS) {
      int zz = z0 + rowi / Y;
      int yy = y0 + rowi % Y;
      int adz = abs(zz - iz), ady = abs(yy - iy);
      float lbz = (adz > 0) ? (float)(adz - 1) * h : 0.0f;
      float lby = (ady > 0) ? (float)(ady - 1) * h : 0.0f;
      float lb2 = lbz*lbz + lby*lby;
      int rowbase = cellofs + (zz*G + yy)*G;
      if (adz == r || ady == r) {
        if (lb2 >= dbest) continue;    // row cannot beat current best
        int s = cs[rowbase + x0], e = cs[rowbase + x1 + 1];
        for (int i = s; i < e; ++i) {
          float4 v = pts[i];
          best = fminf(best, fmaf(v.z, m2z, fmaf(v.y, m2y, fmaf(v.x, m2x, v.w))));
        }
      } else {
        float lbx = (float)(r - 1) * h;
        if (lb2 + lbx*lbx >= dbest) continue;
        if (ix - r >= 0) {
          int cix = rowbase + ix - r;
          int s = cs[cix], e = cs[cix + 1];
          for (int i = s; i < e; ++i) {
            float4 v = pts[i];
            best = fminf(best, fmaf(v.z, m2z, fmaf(v.y, m2y, fmaf(v.x, m2x, v.w))));
          }
        }
        if (ix + r <= G - 1) {
          int cix = rowbase + ix + r;
          int s = cs[cix], e = cs[cix + 1];
          for (int i = s; i < e; ++i) {
            float4 v = pts[i];
            best = fminf(best, fmaf(v.z, m2z, fmaf(v.y, m2y, fmaf(v.x, m2x, v.w))));
          }
        }
      }
    }
  }
  return group_min16(best);
}

// ---------------- fused queries (grid-stride over fwd+rev groups) + last-block final
__global__ __launch_bounds__(256) void query_kernel(
    const float* __restrict__ fp, const float4* __restrict__ sb4,
    const int* __restrict__ cs, const float4* __restrict__ sorted,
    float* __restrict__ acc, float* __restrict__ out,
    int NSF, int NFP, int nsamp, int sampBase) {
  const float h1 = (G1HI - G1LO) / (float)G1;
  const float h2 = (G2HI - G2LO) / (float)G2;
  int lane = threadIdx.x & (GS - 1);
  int grpInBlk = threadIdx.x / GS;       // 0..15
  const int grpsPerBlk = 256 / GS;       // 16
  int totalGroups = NSF + nsamp;
  float facc = 0.0f, racc = 0.0f, rmaxv = 0.0f;
  for (int g = blockIdx.x * grpsPerBlk + grpInBlk; g < totalGroups;
       g += gridDim.x * grpsPerBlk) {
    if (g < NSF) {
      float4 s = sb4[g];
      float best = nn_group(s.x, s.y, s.z, s.w, cs, sorted, G2, G2LO, h2, NCELL1, lane);
      if (lane == 0) {
        float mind = sqrtf(fmaxf(best + s.w, 0.0f));
        float p = (g < NFP) ? fp[g] : 0.0f;
        facc += p * mind;
      }
    } else {
      int sid = g - NSF;
      float4 s = sorted[sampBase + sid];
      float q2 = s.x*s.x + s.y*s.y + s.z*s.z;
      float best = nn_group(s.x, s.y, s.z, q2, cs, sorted, G1, G1LO, h1, 0, lane);
      if (lane == 0) {
        float d = sqrtf(fmaxf(best + q2, 0.0f));
        racc += s.w * d;
        rmaxv = fmaxf(rmaxv, d);
      }
    }
  }
  // block reduce (non-leader lanes hold 0)
  __shared__ float sF[4], sR[4], sM[4];
  __shared__ int isLast;
  __shared__ float stash[4];
  for (int o = 32; o > 0; o >>= 1) {
    facc += __shfl_down(facc, o);
    racc += __shfl_down(racc, o);
    rmaxv = fmaxf(rmaxv, __shfl_down(rmaxv, o));
  }
  int wid = threadIdx.x >> 6;
  if ((threadIdx.x & 63) == 0) { sF[wid] = facc; sR[wid] = racc; sM[wid] = rmaxv; }
  __syncthreads();
  if (threadIdx.x == 0) {
    float tf = sF[0] + sF[1] + sF[2] + sF[3];
    float tr = sR[0] + sR[1] + sR[2] + sR[3];
    float tm = fmaxf(fmaxf(sM[0], sM[1]), fmaxf(sM[2], sM[3]));
    int slot = (blockIdx.x & 63) * 16;
    atomicAdd(&acc[slot], tf);
    atomicAdd(&acc[1024 + slot], tr);
    atomicMax((int*)acc + 2048 + slot, __float_as_int(tm));
    __threadfence();
    int old = atomicAdd((int*)acc + 3072, 1);
    isLast = (old == (int)gridDim.x - 1) ? 1 : 0;
  }
  __syncthreads();
  if (!isLast) return;

  // ---- final: last block reads slots via atomic RMWs (coherent), reduces, writes out ----
  __shared__ float red[256];
  int t = threadIdx.x;
  float fsum = 0.0f, rsum = 0.0f, rmx = 0.0f;
  if (t < 64)        fsum = atomicAdd(&acc[t * 16], 0.0f);
  else if (t < 128)  rsum = atomicAdd(&acc[1024 + (t - 64) * 16], 0.0f);
  else if (t < 192)  rmx  = __int_as_float(atomicMax((int*)acc + 2048 + (t - 128) * 16, 0));
  float sfp = 0.0f;
  for (int i = t; i < NSF; i += 256) sfp += (i < NFP) ? fp[i] : 0.0f;

  red[t] = fsum; __syncthreads();
  for (int o = 128; o > 0; o >>= 1) { if (t < o) red[t] += red[t + o]; __syncthreads(); }
  if (t == 0) stash[0] = red[0];
  __syncthreads();
  red[t] = rsum; __syncthreads();
  for (int o = 128; o > 0; o >>= 1) { if (t < o) red[t] += red[t + o]; __syncthreads(); }
  if (t == 0) stash[1] = red[0];
  __syncthreads();
  red[t] = rmx; __syncthreads();
  for (int o = 128; o > 0; o >>= 1) { if (t < o) red[t] = fmaxf(red[t], red[t + o]); __syncthreads(); }
  if (t == 0) stash[2] = red[0];
  __syncthreads();
  red[t] = sfp; __syncthreads();
  for (int o = 128; o > 0; o >>= 1) { if (t < o) red[t] += red[t + o]; __syncthreads(); }
  if (t == 0) {
    float fwd = stash[0] + PENALTY * ((float)NSF - red[0]);
    float rev = stash[1] * (REV_SCALE / (stash[2] + EPSF));
    out[0] = fwd + rev;
  }
}

extern "C" void kernel_launch(void* const* d_in, const int* in_sizes, int n_in,
                              void* d_out, int out_size, void* d_ws, size_t ws_size,
                              hipStream_t stream) {
  const float* ov  = (const float*)d_in[0];
  const int*   ofc = (const int*)  d_in[1];
  const float* sv  = (const float*)d_in[2];
  const int*   sfc = (const int*)  d_in[3];
  const float* fp  = (const float*)d_in[4];
  float* out = (float*)d_out;

  int NOV = in_sizes[0] / 3;
  int NOF = in_sizes[1] / 3;
  int NSF = in_sizes[3] / 3;
  int NFP = in_sizes[4];
  int nsamp = NSF * NUM_SAMPLES;

  // ws layout: [acc 16KB (incl. done ctr + barrier ctrs)][cnt][cs][cur][bsum][float4 arrays]
  char* w = (char*)d_ws;
  float* acc = (float*)w;       w += ACC_FLOATS * 4;             // 16 KB, memset below
  int*   cnt = (int*)w;         w += (size_t)NTOTALL * 4;
  int*   cs  = (int*)w;         w += (size_t)(NTOTALL + 16) * 4;
  int*   cur = (int*)w;         w += (size_t)NTOTALL * 4;
  int*   bsum = (int*)w;        w += 1024;
  float4* ob4    = (float4*)w;  w += (size_t)NOF * 16;
  float4* sb4    = (float4*)w;  w += (size_t)NSF * 16;
  float4* ov4    = (float4*)w;  w += (size_t)NOV * 16;
  float4* sorted = (float4*)w;  w += (size_t)(NOV + NOF + nsamp) * 16;
  int* barctr = (int*)acc + 3080;

  hipMemsetAsync(acc, 0, ACC_FLOATS * 4, stream);  // acc slots + done ctr + barrier ctrs

  hipLaunchKernelGGL(build_kernel, dim3(NB), dim3(256), 0, stream,
                     ov, ofc, sv, sfc, fp, ob4, sb4, ov4, sorted,
                     cnt, cs, cur, bsum, barctr, NOF, NSF, NOV, NFP, nsamp);

  hipLaunchKernelGGL(query_kernel, dim3(QBLOCKS), dim3(256), 0, stream,
                     fp, sb4, cs, sorted, acc, out, NSF, NFP, nsamp, NOV + NOF);
}

// Round 6
// 375.240 us; speedup vs baseline: 1.1286x; 1.1286x over previous
//
#include <hip/hip_runtime.h>
#include <stdint.h>
#include <float.h>

#define NUM_SAMPLES 50
#define EPSF 1e-8f
#define PENALTY 1e-4f
#define REV_SCALE 0.1f

// grid 1: original vertices (N(0,1) coords)
#define G1 48
#define G1LO -5.0f
#define G1HI 5.0f
#define NCELL1 (G1*G1*G1)
// grid 2: original-face barycenters (sigma ~0.577)
#define G2 48
#define G2LO -3.5f
#define G2HI 3.5f
#define NCELL2 (G2*G2*G2)
// grid 3: sample-point buckets (query sorting only)
#define G3 32
#define G3LO -5.0f
#define G3HI 5.0f
#define NCELL3 (G3*G3*G3)

#define NTOTALL (NCELL1 + NCELL2 + NCELL3)   // 253952
#define SCAN_BLOCKS (NTOTALL / 1024)         // 248
static_assert(NTOTALL % 1024 == 0, "scan tiling");

#define GS 16          // lanes per query group
#define QBLOCKS 2048   // query kernel grid (divisible by 8)

// acc region (floats): fwd slots [0..1023] stride16; rev [1024..2047]; max bits [2048..3071];
// done counter int at [3072]. 16 KB.
#define ACC_FLOATS 4096

// ---------------- JAX threefry2x32 (exact) ----------------
__device__ __forceinline__ uint32_t rotl32(uint32_t v, int d) {
  return (v << d) | (v >> (32 - d));
}

__device__ __forceinline__ void threefry2x32(uint32_t k0, uint32_t k1,
                                             uint32_t x0, uint32_t x1,
                                             uint32_t& o0, uint32_t& o1) {
  const uint32_t k2 = k0 ^ k1 ^ 0x1BD11BDAu;
  x0 += k0; x1 += k1;
#define TF_ROUND(r) { x0 += x1; x1 = rotl32(x1, (r)); x1 ^= x0; }
  TF_ROUND(13) TF_ROUND(15) TF_ROUND(26) TF_ROUND(6)
  x0 += k1; x1 += k2 + 1u;
  TF_ROUND(17) TF_ROUND(29) TF_ROUND(16) TF_ROUND(24)
  x0 += k2; x1 += k0 + 2u;
  TF_ROUND(13) TF_ROUND(15) TF_ROUND(26) TF_ROUND(6)
  x0 += k0; x1 += k1 + 3u;
  TF_ROUND(17) TF_ROUND(29) TF_ROUND(16) TF_ROUND(24)
  x0 += k1; x1 += k2 + 4u;
  TF_ROUND(13) TF_ROUND(15) TF_ROUND(26) TF_ROUND(6)
  x0 += k2; x1 += k0 + 5u;
#undef TF_ROUND
  o0 = x0; o1 = x1;
}

__device__ __forceinline__ float bits_to_uniform(uint32_t bits) {
  return __uint_as_float((bits >> 9) | 0x3f800000u) - 1.0f;
}

__device__ __forceinline__ float jax_uniform_at(uint32_t k0, uint32_t k1, uint32_t idx) {
  uint32_t o0, o1;
  threefry2x32(k0, k1, 0u, idx, o0, o1);
  return bits_to_uniform(o0 ^ o1);
}

__device__ __forceinline__ int cell_coord(float p, float lo, float invh, int G) {
  int i = (int)floorf((p - lo) * invh);
  return min(max(i, 0), G - 1);
}

// sample id -> position + weight (exact JAX RNG; partitionable split of key(42))
__device__ __forceinline__ float4 gen_sample(int id, const float* __restrict__ sv,
                                             const int* __restrict__ sfc,
                                             const float* __restrict__ fp, int NFP) {
  int face = id / NUM_SAMPLES;
  uint32_t a0, a1, b0, b1;
  threefry2x32(0u, 42u, 0u, 0u, a0, a1);  // rk1
  threefry2x32(0u, 42u, 0u, 1u, b0, b1);  // rk2
  float r1 = jax_uniform_at(a0, a1, (uint32_t)id);
  float r2 = jax_uniform_at(b0, b1, (uint32_t)id);
  float sr1 = sqrtf(r1);
  float ca = 1.0f - sr1;
  float cb = sr1 * (1.0f - r2);
  float cc = sr1 * r2;
  int va = sfc[3*face], vb = sfc[3*face+1], vc = sfc[3*face+2];
  float px = ca*sv[3*va]   + cb*sv[3*vb]   + cc*sv[3*vc];
  float py = ca*sv[3*va+1] + cb*sv[3*vb+1] + cc*sv[3*vc+1];
  float pz = ca*sv[3*va+2] + cb*sv[3*vb+2] + cc*sv[3*vc+2];
  float w = (face < NFP) ? fp[face] : 0.0f;
  return make_float4(px, py, pz, w);
}

// ---------------- prep: barycenters + vertex float4 + histograms (3 grids)
__global__ __launch_bounds__(256) void prep_kernel(
    const float* __restrict__ ov, const int* __restrict__ ofc,
    const float* __restrict__ sv, const int* __restrict__ sfc,
    const float* __restrict__ fp,
    float4* __restrict__ ob4, float4* __restrict__ sb4, float4* __restrict__ ov4,
    int* __restrict__ cnt, int NOF, int NSF, int NOV, int NFP, int nsamp) {
  int i = blockIdx.x * blockDim.x + threadIdx.x;
  int total = NOF + NSF + NOV + nsamp;
  if (i >= total) return;
  if (i < NOF) {
    int a = ofc[3*i], b = ofc[3*i+1], c = ofc[3*i+2];
    float x = (ov[3*a]   + ov[3*b]   + ov[3*c])   / 3.0f;
    float y = (ov[3*a+1] + ov[3*b+1] + ov[3*c+1]) / 3.0f;
    float z = (ov[3*a+2] + ov[3*b+2] + ov[3*c+2]) / 3.0f;
    ob4[i] = make_float4(x, y, z, x*x + y*y + z*z);
    const float invh = (float)G2 / (G2HI - G2LO);
    int cx = cell_coord(x, G2LO, invh, G2);
    int cy = cell_coord(y, G2LO, invh, G2);
    int cz = cell_coord(z, G2LO, invh, G2);
    atomicAdd(&cnt[NCELL1 + (cz*G2 + cy)*G2 + cx], 1);
  } else if (i < NOF + NSF) {
    int j = i - NOF;
    int a = sfc[3*j], b = sfc[3*j+1], c = sfc[3*j+2];
    float x = (sv[3*a]   + sv[3*b]   + sv[3*c])   / 3.0f;
    float y = (sv[3*a+1] + sv[3*b+1] + sv[3*c+1]) / 3.0f;
    float z = (sv[3*a+2] + sv[3*b+2] + sv[3*c+2]) / 3.0f;
    sb4[j] = make_float4(x, y, z, x*x + y*y + z*z);
  } else if (i < NOF + NSF + NOV) {
    int j = i - NOF - NSF;
    float x = ov[3*j], y = ov[3*j+1], z = ov[3*j+2];
    ov4[j] = make_float4(x, y, z, x*x + y*y + z*z);
    const float invh = (float)G1 / (G1HI - G1LO);
    int cx = cell_coord(x, G1LO, invh, G1);
    int cy = cell_coord(y, G1LO, invh, G1);
    int cz = cell_coord(z, G1LO, invh, G1);
    atomicAdd(&cnt[(cz*G1 + cy)*G1 + cx], 1);
  } else {
    int j = i - NOF - NSF - NOV;
    float4 s = gen_sample(j, sv, sfc, fp, NFP);
    const float invh = (float)G3 / (G3HI - G3LO);
    int cx = cell_coord(s.x, G3LO, invh, G3);
    int cy = cell_coord(s.y, G3LO, invh, G3);
    int cz = cell_coord(s.z, G3LO, invh, G3);
    atomicAdd(&cnt[NCELL1 + NCELL2 + (cz*G3 + cy)*G3 + cx], 1);
  }
}

// ---------------- fused parallel scan (publish aggregate + parallel poll)
// All SCAN_BLOCKS=248 blocks are co-resident on 256 CUs -> no deadlock.
__global__ __launch_bounds__(256) void scan_kernel(
    const int4* __restrict__ cnt4, unsigned long long* __restrict__ gsum,
    int* __restrict__ cs, int* __restrict__ cur) {
  __shared__ int lds[256];
  __shared__ int wsum[4];
  __shared__ int boffS;
  int t = threadIdx.x;
  int gid = blockIdx.x * 256 + t;
  int4 c = cnt4[gid];
  int s01 = c.x + c.y;
  int tsum = s01 + c.z + c.w;
  lds[t] = tsum;
  __syncthreads();
  for (int d = 1; d < 256; d <<= 1) {
    int u = (t >= d) ? lds[t - d] : 0;
    __syncthreads();
    lds[t] += u;
    __syncthreads();
  }
  int incl = lds[t];
  int agg  = lds[255];
  if (t == 0)
    atomicExch(&gsum[blockIdx.x], (1ULL << 63) | (unsigned long long)(unsigned)agg);
  // parallel poll of all predecessor aggregates
  int pre = 0;
  if (t < (int)blockIdx.x) {
    unsigned long long v;
    do { v = atomicAdd(&gsum[t], 0ULL); } while (!(v >> 63));
    pre = (int)(v & 0xFFFFFFFFULL);
  }
  for (int o = 32; o > 0; o >>= 1) pre += __shfl_down(pre, o);
  if ((t & 63) == 0) wsum[t >> 6] = pre;
  __syncthreads();
  if (t == 0) boffS = wsum[0] + wsum[1] + wsum[2] + wsum[3];
  __syncthreads();
  int base = boffS + incl - tsum;
  int4 o4;
  o4.x = base;
  o4.y = base + c.x;
  o4.z = base + s01;
  o4.w = base + s01 + c.z;
  ((int4*)cs)[gid] = o4;
  ((int4*)cur)[gid] = o4;
  if (blockIdx.x == gridDim.x - 1 && t == 255) cs[NTOTALL] = boffS + incl;
}

// ---------------- scatter points + samples into cell-sorted order
__global__ __launch_bounds__(256) void scatter_kernel(
    const float4* __restrict__ ov4, const float4* __restrict__ ob4,
    const float* __restrict__ sv, const int* __restrict__ sfc,
    const float* __restrict__ fp,
    int* __restrict__ cur, float4* __restrict__ sorted,
    int NOV, int NOF, int NFP, int nsamp) {
  int i = blockIdx.x * blockDim.x + threadIdx.x;
  if (i >= NOV + NOF + nsamp) return;
  float4 p; int c;
  if (i < NOV) {
    p = ov4[i];
    const float invh = (float)G1 / (G1HI - G1LO);
    int cx = cell_coord(p.x, G1LO, invh, G1);
    int cy = cell_coord(p.y, G1LO, invh, G1);
    int cz = cell_coord(p.z, G1LO, invh, G1);
    c = (cz*G1 + cy)*G1 + cx;
  } else if (i < NOV + NOF) {
    p = ob4[i - NOV];
    const float invh = (float)G2 / (G2HI - G2LO);
    int cx = cell_coord(p.x, G2LO, invh, G2);
    int cy = cell_coord(p.y, G2LO, invh, G2);
    int cz = cell_coord(p.z, G2LO, invh, G2);
    c = NCELL1 + (cz*G2 + cy)*G2 + cx;
  } else {
    int j = i - NOV - NOF;
    p = gen_sample(j, sv, sfc, fp, NFP);   // regenerate (saves a 4 MB staging array)
    const float invh = (float)G3 / (G3HI - G3LO);
    int cx = cell_coord(p.x, G3LO, invh, G3);
    int cy = cell_coord(p.y, G3LO, invh, G3);
    int cz = cell_coord(p.z, G3LO, invh, G3);
    c = NCELL1 + NCELL2 + (cz*G3 + cy)*G3 + cx;
  }
  int idx = atomicAdd(&cur[c], 1);
  sorted[idx] = p;
}

// ---------------- row-parallel cooperative 1-NN: lanes own ring ROWS (parallel cs chains)
__device__ __forceinline__ float group_min16(float v) {
  for (int o = 8; o > 0; o >>= 1) v = fminf(v, __shfl_xor(v, o, 16));
  return v;
}

__device__ float nn_group(float px, float py, float pz, float q2,
                          const int* __restrict__ cs, const float4* __restrict__ pts,
                          int G, float lo, float h, int cellofs, int lane) {
  const float invh = 1.0f / h;
  int ix = cell_coord(px, lo, invh, G);
  int iy = cell_coord(py, lo, invh, G);
  int iz = cell_coord(pz, lo, invh, G);
  float m2x = -2.0f*px, m2y = -2.0f*py, m2z = -2.0f*pz;
  float best = FLT_MAX;  // per-lane partial of t = d^2 - q2

  // r = 0: cooperative over the home cell
  {
    int cix = cellofs + (iz*G + iy)*G + ix;
    int s = cs[cix], e = cs[cix + 1];
    for (int i = s + lane; i < e; i += GS) {
      float4 v = pts[i];
      best = fminf(best, fmaf(v.z, m2z, fmaf(v.y, m2y, fmaf(v.x, m2x, v.w))));
    }
  }
  for (int r = 1; r < G; ++r) {
    float bmin = group_min16(best);
    float bd = (float)(r - 1) * h;
    if (bmin + q2 <= bd * bd) break;   // exact termination
    float dbest = bmin + q2;           // current best d^2 (inf if none yet)
    int z0 = max(iz - r, 0), z1 = min(iz + r, G - 1);
    int y0 = max(iy - r, 0), y1 = min(iy + r, G - 1);
    int x0 = max(ix - r, 0), x1 = min(ix + r, G - 1);
    int Y = y1 - y0 + 1;
    int nrows = Y * (z1 - z0 + 1);
    for (int rowi = lane; rowi < nrows; rowi += GS) {
      int zz = z0 + rowi / Y;
      int yy = y0 + rowi % Y;
      int adz = abs(zz - iz), ady = abs(yy - iy);
      float lbz = (adz > 0) ? (float)(adz - 1) * h : 0.0f;
      float lby = (ady > 0) ? (float)(ady - 1) * h : 0.0f;
      float lb2 = lbz*lbz + lby*lby;
      int rowbase = cellofs + (zz*G + yy)*G;
      if (adz == r || ady == r) {
        if (lb2 >= dbest) continue;    // row cannot beat current best
        int s = cs[rowbase + x0], e = cs[rowbase + x1 + 1];
        for (int i = s; i < e; ++i) {
          float4 v = pts[i];
          best = fminf(best, fmaf(v.z, m2z, fmaf(v.y, m2y, fmaf(v.x, m2x, v.w))));
        }
      } else {
        float lbx = (float)(r - 1) * h;
        if (lb2 + lbx*lbx >= dbest) continue;
        if (ix - r >= 0) {
          int cix = rowbase + ix - r;
          int s = cs[cix], e = cs[cix + 1];
          for (int i = s; i < e; ++i) {
            float4 v = pts[i];
            best = fminf(best, fmaf(v.z, m2z, fmaf(v.y, m2y, fmaf(v.x, m2x, v.w))));
          }
        }
        if (ix + r <= G - 1) {
          int cix = rowbase + ix + r;
          int s = cs[cix], e = cs[cix + 1];
          for (int i = s; i < e; ++i) {
            float4 v = pts[i];
            best = fminf(best, fmaf(v.z, m2z, fmaf(v.y, m2y, fmaf(v.x, m2x, v.w))));
          }
        }
      }
    }
  }
  return group_min16(best);
}

// ---------------- queries: contiguous per-block ranges, XCD-swizzled + last-block final
__global__ __launch_bounds__(256) void query_kernel(
    const float* __restrict__ fp, const float4* __restrict__ sb4,
    const int* __restrict__ cs, const float4* __restrict__ sorted,
    float* __restrict__ acc, float* __restrict__ out,
    int NSF, int NFP, int nsamp, int sampBase) {
  const float h1 = (G1HI - G1LO) / (float)G1;
  const float h2 = (G2HI - G2LO) / (float)G2;
  int lane = threadIdx.x & (GS - 1);
  int grpInBlk = threadIdx.x / GS;       // 0..15
  int totalGroups = NSF + nsamp;
  // XCD-contiguous logical block: assumed XCD = blockIdx % 8; give each XCD a
  // contiguous eighth of the (spatially sorted) query range -> per-XCD L2 slice fits 4MB.
  int logical = (blockIdx.x & 7) * (QBLOCKS / 8) + (blockIdx.x >> 3);
  int per = (totalGroups + QBLOCKS - 1) / QBLOCKS;   // groups per block, contiguous
  int gBase = logical * per;
  int gEnd = min(gBase + per, totalGroups);
  float facc = 0.0f, racc = 0.0f, rmaxv = 0.0f;
  for (int g = gBase + grpInBlk; g < gEnd; g += 256 / GS) {
    if (g < NSF) {
      float4 s = sb4[g];
      float best = nn_group(s.x, s.y, s.z, s.w, cs, sorted, G2, G2LO, h2, NCELL1, lane);
      if (lane == 0) {
        float mind = sqrtf(fmaxf(best + s.w, 0.0f));
        float p = (g < NFP) ? fp[g] : 0.0f;
        facc += p * mind;
      }
    } else {
      int sid = g - NSF;
      float4 s = sorted[sampBase + sid];
      float q2 = s.x*s.x + s.y*s.y + s.z*s.z;
      float best = nn_group(s.x, s.y, s.z, q2, cs, sorted, G1, G1LO, h1, 0, lane);
      if (lane == 0) {
        float d = sqrtf(fmaxf(best + q2, 0.0f));
        racc += s.w * d;
        rmaxv = fmaxf(rmaxv, d);
      }
    }
  }
  // block reduce (non-leader lanes hold 0)
  __shared__ float sF[4], sR[4], sM[4];
  __shared__ int isLast;
  __shared__ float stash[4];
  for (int o = 32; o > 0; o >>= 1) {
    facc += __shfl_down(facc, o);
    racc += __shfl_down(racc, o);
    rmaxv = fmaxf(rmaxv, __shfl_down(rmaxv, o));
  }
  int wid = threadIdx.x >> 6;
  if ((threadIdx.x & 63) == 0) { sF[wid] = facc; sR[wid] = racc; sM[wid] = rmaxv; }
  __syncthreads();
  if (threadIdx.x == 0) {
    float tf = sF[0] + sF[1] + sF[2] + sF[3];
    float tr = sR[0] + sR[1] + sR[2] + sR[3];
    float tm = fmaxf(fmaxf(sM[0], sM[1]), fmaxf(sM[2], sM[3]));
    int slot = (blockIdx.x & 63) * 16;
    atomicAdd(&acc[slot], tf);
    atomicAdd(&acc[1024 + slot], tr);
    atomicMax((int*)acc + 2048 + slot, __float_as_int(tm));
    __threadfence();
    int old = atomicAdd((int*)acc + 3072, 1);
    isLast = (old == (int)gridDim.x - 1) ? 1 : 0;
  }
  __syncthreads();
  if (!isLast) return;

  // ---- final: last block reads slots via atomic RMWs (coherent), reduces, writes out ----
  __shared__ float red[256];
  int t = threadIdx.x;
  float fsum = 0.0f, rsum = 0.0f, rmx = 0.0f;
  if (t < 64)        fsum = atomicAdd(&acc[t * 16], 0.0f);
  else if (t < 128)  rsum = atomicAdd(&acc[1024 + (t - 64) * 16], 0.0f);
  else if (t < 192)  rmx  = __int_as_float(atomicMax((int*)acc + 2048 + (t - 128) * 16, 0));
  float sfp = 0.0f;
  for (int i = t; i < NSF; i += 256) sfp += (i < NFP) ? fp[i] : 0.0f;

  red[t] = fsum; __syncthreads();
  for (int o = 128; o > 0; o >>= 1) { if (t < o) red[t] += red[t + o]; __syncthreads(); }
  if (t == 0) stash[0] = red[0];
  __syncthreads();
  red[t] = rsum; __syncthreads();
  for (int o = 128; o > 0; o >>= 1) { if (t < o) red[t] += red[t + o]; __syncthreads(); }
  if (t == 0) stash[1] = red[0];
  __syncthreads();
  red[t] = rmx; __syncthreads();
  for (int o = 128; o > 0; o >>= 1) { if (t < o) red[t] = fmaxf(red[t], red[t + o]); __syncthreads(); }
  if (t == 0) stash[2] = red[0];
  __syncthreads();
  red[t] = sfp; __syncthreads();
  for (int o = 128; o > 0; o >>= 1) { if (t < o) red[t] += red[t + o]; __syncthreads(); }
  if (t == 0) {
    float fwd = stash[0] + PENALTY * ((float)NSF - red[0]);
    float rev = stash[1] * (REV_SCALE / (stash[2] + EPSF));
    out[0] = fwd + rev;
  }
}

extern "C" void kernel_launch(void* const* d_in, const int* in_sizes, int n_in,
                              void* d_out, int out_size, void* d_ws, size_t ws_size,
                              hipStream_t stream) {
  const float* ov  = (const float*)d_in[0];
  const int*   ofc = (const int*)  d_in[1];
  const float* sv  = (const float*)d_in[2];
  const int*   sfc = (const int*)  d_in[3];
  const float* fp  = (const float*)d_in[4];
  float* out = (float*)d_out;

  int NOV = in_sizes[0] / 3;
  int NOF = in_sizes[1] / 3;
  int NSF = in_sizes[3] / 3;
  int NFP = in_sizes[4];
  int nsamp = NSF * NUM_SAMPLES;

  // ws layout: [acc 16KB][gsum 2KB][cnt][cs][cur][bsum pad][float4 arrays]
  char* w = (char*)d_ws;
  float* acc = (float*)w;                            w += ACC_FLOATS * 4;  // 16 KB
  unsigned long long* gsum = (unsigned long long*)w; w += 2048;            // 2 KB
  int*   cnt = (int*)w;                              w += (size_t)NTOTALL * 4;
  size_t zeroBytes = (size_t)(w - (char*)d_ws);      // acc + gsum + cnt contiguous
  int*   cs  = (int*)w;                              w += (size_t)(NTOTALL + 16) * 4;
  int*   cur = (int*)w;                              w += (size_t)NTOTALL * 4;
  float4* ob4    = (float4*)w;  w += (size_t)NOF * 16;
  float4* sb4    = (float4*)w;  w += (size_t)NSF * 16;
  float4* ov4    = (float4*)w;  w += (size_t)NOV * 16;
  float4* sorted = (float4*)w;  w += (size_t)(NOV + NOF + nsamp) * 16;

  hipMemsetAsync(d_ws, 0, zeroBytes, stream);

  int total = NOF + NSF + NOV + nsamp;
  hipLaunchKernelGGL(prep_kernel, dim3((total + 255) / 256), dim3(256), 0, stream,
                     ov, ofc, sv, sfc, fp, ob4, sb4, ov4, cnt, NOF, NSF, NOV, NFP, nsamp);

  hipLaunchKernelGGL(scan_kernel, dim3(SCAN_BLOCKS), dim3(256), 0, stream,
                     (const int4*)cnt, gsum, cs, cur);

  hipLaunchKernelGGL(scatter_kernel, dim3((NOV + NOF + nsamp + 255) / 256), dim3(256), 0, stream,
                     ov4, ob4, sv, sfc, fp, cur, sorted, NOV, NOF, NFP, nsamp);

  hipLaunchKernelGGL(query_kernel, dim3(QBLOCKS), dim3(256), 0, stream,
                     fp, sb4, cs, sorted, acc, out, NSF, NFP, nsamp, NOV + NOF);
}